// Round 13
// baseline (338.059 us; speedup 1.0000x reference)
//
#include <hip/hip_runtime.h>

#define BATCH 2
#define SEQ 2048
#define EMBED 2048
#define NHEADS 32
#define NKV 8
#define HDIM 64
#define QKV_LD 3072  // fused [Q(2048) | K(512) | V(512)] row stride
#define LOG2E 1.44269504088896f

typedef __attribute__((ext_vector_type(8))) short short8;
typedef __attribute__((ext_vector_type(4))) float f32x4;

__device__ inline float hw_exp2(float x) { return __builtin_amdgcn_exp2f(x); }

__device__ inline ushort f2bf(float f) {
  union { float f; unsigned u; } v{f};
  unsigned r = v.u + 0x7FFF + ((v.u >> 16) & 1);
  return (ushort)(r >> 16);
}
__device__ inline float bf2f(ushort u) {
  union { unsigned u; float f; } v{((unsigned)u) << 16};
  return v.f;
}
__device__ inline unsigned fbits(float f) {
  union { float f; unsigned u; } v{f};
  return v.u;
}

__device__ inline void gload16(const ushort* g, ushort* l) {
  __builtin_amdgcn_global_load_lds(
      (const __attribute__((address_space(1))) unsigned*)g,
      (__attribute__((address_space(3))) unsigned*)l, 16, 0, 0);
}

// ---------------- fused fp32 -> bf16 convert (all 5 tensors, 1 launch) ----------------
__global__ __launch_bounds__(256) void cvt_all(const float* __restrict__ x,
                                               const float* __restrict__ wq,
                                               const float* __restrict__ wk,
                                               const float* __restrict__ wv,
                                               const float* __restrict__ wo,
                                               ushort* __restrict__ xb,
                                               ushort* __restrict__ wqkv,
                                               ushort* __restrict__ wob) {
  size_t e = (size_t)(blockIdx.x * blockDim.x + threadIdx.x) * 8;
  const float* src;
  ushort* dst;
  if (e < 8388608u) { src = x + e; dst = xb + e; }
  else if (e < 12582912u) { size_t o = e - 8388608u; src = wq + o; dst = wqkv + o; }
  else if (e < 13631488u) { size_t o = e - 12582912u; src = wk + o; dst = wqkv + 4194304u + o; }
  else if (e < 14680064u) { size_t o = e - 13631488u; src = wv + o; dst = wqkv + 5242880u + o; }
  else { size_t o = e - 14680064u; src = wo + o; dst = wob + o; }
  float4 v0 = ((const float4*)src)[0];
  float4 v1 = ((const float4*)src)[1];
  union { uint4 v; ushort u[8]; } pk;
  pk.u[0] = f2bf(v0.x); pk.u[1] = f2bf(v0.y); pk.u[2] = f2bf(v0.z); pk.u[3] = f2bf(v0.w);
  pk.u[4] = f2bf(v1.x); pk.u[5] = f2bf(v1.y); pk.u[6] = f2bf(v1.z); pk.u[7] = f2bf(v1.w);
  *(uint4*)dst = pk.v;
}

// ---------------- counted-vmcnt 3-buffer bf16 GEMM: C[M,N] = A * B^T ----------------
// v14 (T4): BK=32 steps, TRIPLE-buffered LDS, vmcnt never drained to 0 in the loop.
// Per step T: wait vmcnt(LPS) (only step T's loads, issued 2 steps ~600cy earlier;
// T+1's stay in flight across the barrier) -> s_barrier -> issue T+2's loads
// (3-4/wave, shallow queue - no v9 bunching) -> 12 ds_reads + 32 MFMA.
// Hazards: stage(T+2) writes buf (T-1)%3 whose readers' MFMAs consumed every
// ds_read before the barrier; each wave's own vmcnt wait precedes the barrier
// so all stages for T are LDS-visible after it. Barriers: 10 -> 2 per 64-K.
// v13 bank swizzle kept (chunk' = chunk ^ ((row>>1)&3), source-and-read XOR).
// MODE=1 (gemm1): RoPE fused in epilogue. BN=128: LDS 72KB -> 2 blocks/CU.
template <int BN, int MODE, typename OutT>
__global__ __launch_bounds__(512) void gemm3b(const ushort* __restrict__ Ag,
                                              const ushort* __restrict__ Bg,
                                              OutT* __restrict__ C,
                                              const float* __restrict__ fc,
                                              const float* __restrict__ fs,
                                              int M, int N, int K) {
  constexpr int NF = BN / 64;  // per-wave 16-col fragments
  __shared__ ushort As[3][256][32];
  __shared__ ushort Bs[3][BN][32];
  const int tid = threadIdx.x;
  const int lane = tid & 63, wave = tid >> 6;
  const int quad = lane >> 4, l16 = lane & 15;
  const int wm = wave >> 2, wn = wave & 3;  // 2M x 4N
  const int m0 = blockIdx.y * 256, n0 = blockIdx.x * BN;
  const int NT = K >> 5;  // BK=32 steps

  // stage one 32-K step: A rows [wave*32,+32) (2 gload16), B 2 or 1 gload16.
  auto stage = [&](int Tn) {
    const int b3 = Tn % 3;
    {
      const int r0 = wave * 32;
      const int lr0 = r0 + (lane >> 2);
      const int sw0 = ((lane & 3) ^ ((lr0 >> 1) & 3)) * 8;
      gload16(Ag + (size_t)(m0 + lr0) * K + Tn * 32 + sw0, &As[b3][r0][0]);
      const int lr1 = lr0 + 16;
      const int sw1 = ((lane & 3) ^ ((lr1 >> 1) & 3)) * 8;
      gload16(Ag + (size_t)(m0 + lr1) * K + Tn * 32 + sw1, &As[b3][r0 + 16][0]);
    }
    if constexpr (BN == 256) {
      const int r0 = wave * 32;
      const int lr0 = r0 + (lane >> 2);
      const int sw0 = ((lane & 3) ^ ((lr0 >> 1) & 3)) * 8;
      gload16(Bg + (size_t)(n0 + lr0) * K + Tn * 32 + sw0, &Bs[b3][r0][0]);
      const int lr1 = lr0 + 16;
      const int sw1 = ((lane & 3) ^ ((lr1 >> 1) & 3)) * 8;
      gload16(Bg + (size_t)(n0 + lr1) * K + Tn * 32 + sw1, &Bs[b3][r0 + 16][0]);
    } else {
      const int r0 = wave * 16;
      const int lr0 = r0 + (lane >> 2);
      const int sw0 = ((lane & 3) ^ ((lr0 >> 1) & 3)) * 8;
      gload16(Bg + (size_t)(n0 + lr0) * K + Tn * 32 + sw0, &Bs[b3][r0][0]);
    }
  };

  f32x4 acc[8][NF] = {};

  // prologue: stage steps 0 and 1
  stage(0);
  stage(1);

  for (int T = 0; T < NT; ++T) {
    const int b3 = T % 3;
    // counted wait: only step T's loads must land; T+1's stay in flight.
    if (T + 1 < NT) {
      if constexpr (BN == 256)
        asm volatile("s_waitcnt vmcnt(4)" ::: "memory");
      else
        asm volatile("s_waitcnt vmcnt(3)" ::: "memory");
    } else {
      asm volatile("s_waitcnt vmcnt(0)" ::: "memory");
    }
    __builtin_amdgcn_sched_barrier(0);
    __builtin_amdgcn_s_barrier();
    __builtin_amdgcn_sched_barrier(0);

    if (T + 2 < NT) stage(T + 2);

    // fragment reads (swizzled chunk), then MFMA (compiler interleaves lgkmcnt)
    short8 bfr[NF];
#pragma unroll
    for (int nf = 0; nf < NF; nf++) {
      const int row = wn * (16 * NF) + nf * 16 + l16;
      const int ch = (quad ^ ((row >> 1) & 3)) * 8;
      bfr[nf] = *(short8*)&Bs[b3][row][ch];
    }
    short8 afr[8];
#pragma unroll
    for (int mf = 0; mf < 8; mf++) {
      const int row = wm * 128 + mf * 16 + l16;
      const int ch = (quad ^ ((row >> 1) & 3)) * 8;
      afr[mf] = *(short8*)&As[b3][row][ch];
    }

    __builtin_amdgcn_s_setprio(1);
#pragma unroll
    for (int mf = 0; mf < 8; mf++)
#pragma unroll
      for (int nf = 0; nf < NF; nf++)
        acc[mf][nf] = __builtin_amdgcn_mfma_f32_16x16x32_bf16(
            afr[mf], bfr[nf], acc[mf][nf], 0, 0, 0);
    __builtin_amdgcn_s_setprio(0);
  }

  // ---------------- epilogue ----------------
  if constexpr (MODE == 1) {
    // fused RoPE (Q/K regions) or passthrough (V region)
    if (n0 < 2560) {
      const float scale = (n0 < 2048) ? 0.125f * LOG2E : 1.0f;
      const int d0 = l16, d1 = l16 + 32;
      const int e0 = l16 + 16, e1 = l16 + 48;
#pragma unroll
      for (int mf = 0; mf < 8; mf++) {
#pragma unroll
        for (int r = 0; r < 4; r++) {
          size_t rg = (size_t)(m0 + wm * 128 + mf * 16 + quad * 4 + r);
          int s = (int)(rg & (SEQ - 1));
          const float* cb = fc + s * HDIM;
          const float* sb = fs + s * HDIM;
          float x0 = acc[mf][0][r], x2 = acc[mf][2][r];
          float y1 = acc[mf][1][r], y3 = acc[mf][3][r];
          float o0 = (x0 * cb[d0] - x2 * sb[d0]) * scale;
          float o2 = (x2 * cb[d1] + x0 * sb[d1]) * scale;
          float o1 = (y1 * cb[e0] - y3 * sb[e0]) * scale;
          float o3 = (y3 * cb[e1] + y1 * sb[e1]) * scale;
          ushort* Cr = (ushort*)C + rg * N + n0 + wn * 64 + l16;
          Cr[0]  = f2bf(o0);
          Cr[16] = f2bf(o1);
          Cr[32] = f2bf(o2);
          Cr[48] = f2bf(o3);
        }
      }
      return;
    }
  }
#pragma unroll
  for (int mf = 0; mf < 8; mf++) {
#pragma unroll
    for (int r = 0; r < 4; r++) {
      size_t rg = (size_t)(m0 + wm * 128 + mf * 16 + quad * 4 + r);
#pragma unroll
      for (int nf = 0; nf < NF; nf++) {
        int cg = n0 + wn * (16 * NF) + nf * 16 + l16;
        if constexpr (sizeof(OutT) == 2)
          C[rg * N + cg] = f2bf(acc[mf][nf][r]);
        else
          C[rg * N + cg] = acc[mf][nf][r];
      }
    }
  }
}

// ---------------- MFMA flash attention v8 (v12, frozen) ----------------
__global__ __launch_bounds__(256, 4) void attn_mfma(const ushort* __restrict__ QKV,
                                                    ushort* __restrict__ O) {
  __shared__ ushort Ks[64][72];     // [key][d]
  __shared__ ushort Vt[64][72];     // [d][key]
  __shared__ ushort Pw[4][16][72];  // per-wave P[q][key], reused per frag
  const int tid = threadIdx.x;
  const int lane = tid & 63, wave = tid >> 6;
  const int quad = lane >> 4, l16 = lane & 15;

  // CU-balanced (qblk, bh) derivation (v6)
  const int bid = blockIdx.x;
  const int qq = bid >> 8;         // quarter 0..3
  const int j4 = (bid >> 6) & 3;   // 0..3
  const int bh = bid & 63;
  const int qblk = (qq >> 1) * 8 + ((qq & 1) ? 7 - j4 : j4);

  const int b = bh >> 5, h = bh & 31, kh = h >> 2;
  const int ntiles = 2 * qblk + 2;          // causal K-range of this 128-row block
  const int wrow = qblk * 128 + wave * 32;  // this wave's first q row (global)

  // Q fragments: f=0 rows [wrow, wrow+16), f=1 rows [wrow+16, wrow+32)
  short8 qf[2][2];
#pragma unroll
  for (int f = 0; f < 2; f++)
#pragma unroll
    for (int c = 0; c < 2; c++)
      qf[f][c] = *(const short8*)(QKV +
          (size_t)(b * SEQ + wrow + f * 16 + l16) * QKV_LD +
          h * HDIM + c * 32 + quad * 8);

  f32x4 o[2][4] = {};
  float m[2] = {-INFINITY, -INFINITY}, l[2] = {0.f, 0.f};  // l is per-LANE partial

  const ushort* Kbase = QKV + (size_t)b * SEQ * QKV_LD + 2048 + kh * HDIM;
  const ushort* Vbase = Kbase + 512;
  const int kp = tid & 31, dg = tid >> 5;

  for (int t = 0; t < ntiles; t++) {
    const int k0 = t * 64;
    __syncthreads();
    {
      const float4* kpp = (const float4*)(Kbase + (size_t)(k0 + lane) * QKV_LD + wave * 16);
      float4 kv0 = kpp[0], kv1 = kpp[1];
      const uint4* va4 = (const uint4*)(Vbase + (size_t)(k0 + 2 * kp) * QKV_LD + dg * 8);
      const uint4* vb4 = (const uint4*)(Vbase + (size_t)(k0 + 2 * kp + 1) * QKV_LD + dg * 8);
      uint4 va = va4[0], vb = vb4[0];
      *(float4*)&Ks[lane][wave * 16] = kv0;
      *(float4*)&Ks[lane][wave * 16 + 8] = kv1;
      const unsigned* vaw = (const unsigned*)&va;
      const unsigned* vbw = (const unsigned*)&vb;
#pragma unroll
      for (int j = 0; j < 8; j++) {
        unsigned pk = (j & 1)
            ? __builtin_amdgcn_perm(vbw[j >> 1], vaw[j >> 1], 0x07060302)
            : __builtin_amdgcn_perm(vbw[j >> 1], vaw[j >> 1], 0x05040100);
        *(unsigned*)&Vt[dg * 8 + j][2 * kp] = pk;
      }
    }
    __syncthreads();

    // wave fully below diagonal? (both frags fully masked -> only staging needed)
    if (k0 > wrow + 31) continue;
    const bool a0 = (k0 <= wrow + 15);  // frag 0 has any active keys

    // QK^T for both frags, kf shared
    f32x4 s0[4], s1[4];
    __builtin_amdgcn_s_setprio(1);
#pragma unroll
    for (int nt = 0; nt < 4; nt++) {
      short8 kf0 = *(short8*)&Ks[nt * 16 + l16][quad * 8];
      short8 kf1 = *(short8*)&Ks[nt * 16 + l16][32 + quad * 8];
      f32x4 z1 = {};
      z1 = __builtin_amdgcn_mfma_f32_16x16x32_bf16(kf0, qf[1][0], z1, 0, 0, 0);
      s1[nt] = __builtin_amdgcn_mfma_f32_16x16x32_bf16(kf1, qf[1][1], z1, 0, 0, 0);
      if (a0) {
        f32x4 z0 = {};
        z0 = __builtin_amdgcn_mfma_f32_16x16x32_bf16(kf0, qf[0][0], z0, 0, 0, 0);
        s0[nt] = __builtin_amdgcn_mfma_f32_16x16x32_bf16(kf1, qf[0][1], z0, 0, 0, 0);
      }
    }
    __builtin_amdgcn_s_setprio(0);

    // causal masking (diagonal region only)
    if (k0 + 63 > wrow + 16) {  // frag 1 diagonal
      const int lim1 = wrow + 16 + l16 - k0;
#pragma unroll
      for (int nt = 0; nt < 4; nt++)
#pragma unroll
        for (int r = 0; r < 4; r++)
          if (nt * 16 + quad * 4 + r > lim1) s1[nt][r] = -INFINITY;
    }
    if (a0 && k0 + 63 > wrow) {  // frag 0 diagonal
      const int lim0 = wrow + l16 - k0;
#pragma unroll
      for (int nt = 0; nt < 4; nt++)
#pragma unroll
        for (int r = 0; r < 4; r++)
          if (nt * 16 + quad * 4 + r > lim0) s0[nt][r] = -INFINITY;
    }

    // online softmax: T13 defer-max + ballot-gated shuffles + per-lane partial l
    auto smx = [&](f32x4 (&s)[4], float& mm, float& ll, f32x4 (&oo)[4]) {
      float mx = s[0][0];
#pragma unroll
      for (int nt = 0; nt < 4; nt++)
#pragma unroll
        for (int r = 0; r < 4; r++) mx = fmaxf(mx, s[nt][r]);
      // __all over lane-partials == __all over row-maxima: shuffle-free gate
      if (!__all(mx <= mm + 8.f)) {
        mx = fmaxf(mx, __shfl_xor(mx, 16));
        mx = fmaxf(mx, __shfl_xor(mx, 32));
        float mnew = fmaxf(mm, mx);
        float al = hw_exp2(mm - mnew);  // row-uniform -> valid for per-lane ll
        mm = mnew;
        ll *= al;
#pragma unroll
        for (int dt = 0; dt < 4; dt++)
#pragma unroll
          for (int r = 0; r < 4; r++) oo[dt][r] *= al;
      }
      float psum = 0.f;
#pragma unroll
      for (int nt = 0; nt < 4; nt++) {
        float p0 = hw_exp2(s[nt][0] - mm), p1 = hw_exp2(s[nt][1] - mm);
        float p2 = hw_exp2(s[nt][2] - mm), p3 = hw_exp2(s[nt][3] - mm);
        psum += (p0 + p1) + (p2 + p3);
        unsigned lo = __builtin_amdgcn_perm(fbits(p1), fbits(p0), 0x07060302);
        unsigned hi = __builtin_amdgcn_perm(fbits(p3), fbits(p2), 0x07060302);
        uint2 pk; pk.x = lo; pk.y = hi;
        *(uint2*)&Pw[wave][l16][nt * 16 + quad * 4] = pk;
      }
      ll += psum;  // per-lane partial; quad-reduced in epilogue
    };

    short8 pf00, pf01, pf10, pf11;
    if (a0) {
      smx(s0, m[0], l[0], o[0]);
      pf00 = *(short8*)&Pw[wave][l16][quad * 8];
      pf01 = *(short8*)&Pw[wave][l16][32 + quad * 8];
    }
    smx(s1, m[1], l[1], o[1]);
    pf10 = *(short8*)&Pw[wave][l16][quad * 8];
    pf11 = *(short8*)&Pw[wave][l16][32 + quad * 8];

    // PV for both frags, vf shared
    __builtin_amdgcn_s_setprio(1);
#pragma unroll
    for (int dt = 0; dt < 4; dt++) {
      short8 vf0 = *(short8*)&Vt[dt * 16 + l16][quad * 8];
      short8 vf1 = *(short8*)&Vt[dt * 16 + l16][32 + quad * 8];
      o[1][dt] = __builtin_amdgcn_mfma_f32_16x16x32_bf16(vf0, pf10, o[1][dt], 0, 0, 0);
      o[1][dt] = __builtin_amdgcn_mfma_f32_16x16x32_bf16(vf1, pf11, o[1][dt], 0, 0, 0);
      if (a0) {
        o[0][dt] = __builtin_amdgcn_mfma_f32_16x16x32_bf16(vf0, pf00, o[0][dt], 0, 0, 0);
        o[0][dt] = __builtin_amdgcn_mfma_f32_16x16x32_bf16(vf1, pf01, o[0][dt], 0, 0, 0);
      }
    }
    __builtin_amdgcn_s_setprio(0);
  }

#pragma unroll
  for (int f = 0; f < 2; f++) {
    // quad-reduce the per-lane partial l (once per frag)
    float lr = l[f];
    lr += __shfl_xor(lr, 16);
    lr += __shfl_xor(lr, 32);
    float inv = 1.0f / lr;
    size_t rowg = (size_t)(b * SEQ + wrow + f * 16 + l16) * EMBED + h * HDIM;
#pragma unroll
    for (int dt = 0; dt < 4; dt++) {
      ushort q0 = f2bf(o[f][dt][0] * inv), q1 = f2bf(o[f][dt][1] * inv);
      ushort q2 = f2bf(o[f][dt][2] * inv), q3 = f2bf(o[f][dt][3] * inv);
      uint2 pk;
      pk.x = (unsigned)q0 | ((unsigned)q1 << 16);
      pk.y = (unsigned)q2 | ((unsigned)q3 << 16);
      *(uint2*)&O[rowg + dt * 16 + quad * 4] = pk;
    }
  }
}

// ---------------- launch ----------------
extern "C" void kernel_launch(void* const* d_in, const int* in_sizes, int n_in,
                              void* d_out, int out_size, void* d_ws, size_t ws_size,
                              hipStream_t stream) {
  const float* x = (const float*)d_in[0];
  const float* fcos = (const float*)d_in[1];
  const float* fsin = (const float*)d_in[2];
  const float* wq = (const float*)d_in[3];
  const float* wk = (const float*)d_in[4];
  const float* wv = (const float*)d_in[5];
  const float* wo = (const float*)d_in[6];
  float* out = (float*)d_out;

  const int M = BATCH * SEQ;  // 4096
  ushort* ws = (ushort*)d_ws;
  ushort* xb = ws;
  ushort* wqkv = xb + (size_t)M * EMBED;
  ushort* wob = wqkv + (size_t)QKV_LD * EMBED;
  ushort* QKVb = wob + (size_t)EMBED * EMBED;
  ushort* Ab = QKVb + (size_t)M * QKV_LD;

  dim3 blk(256);
  cvt_all<<<9216, blk, 0, stream>>>(x, wq, wk, wv, wo, xb, wqkv, wob);

  // QKV projection + fused RoPE: counted-vmcnt 3-buffer GEMM (192 blocks)
  gemm3b<256, 1, ushort><<<dim3(QKV_LD / 256, M / 256), dim3(512), 0, stream>>>(
      xb, wqkv, QKVb, fcos, fsin, M, QKV_LD, EMBED);

  attn_mfma<<<dim3(1024), blk, 0, stream>>>(QKVb, Ab);

  // output projection: counted-vmcnt 3-buffer GEMM (256 blocks, 72KB -> 2/CU)
  gemm3b<128, 0, float><<<dim3(EMBED / 128, M / 256), dim3(512), 0, stream>>>(
      Ab, wob, out, nullptr, nullptr, M, EMBED, EMBED);
}

// Round 14
// 305.732 us; speedup vs baseline: 1.1057x; 1.1057x over previous
//
#include <hip/hip_runtime.h>

#define BATCH 2
#define SEQ 2048
#define EMBED 2048
#define NHEADS 32
#define NKV 8
#define HDIM 64
#define QKV_LD 3072  // fused [Q(2048) | K(512) | V(512)] row stride
#define LOG2E 1.44269504088896f

typedef __attribute__((ext_vector_type(8))) short short8;
typedef __attribute__((ext_vector_type(4))) float f32x4;

__device__ inline float hw_exp2(float x) { return __builtin_amdgcn_exp2f(x); }

__device__ inline ushort f2bf(float f) {
  union { float f; unsigned u; } v{f};
  unsigned r = v.u + 0x7FFF + ((v.u >> 16) & 1);
  return (ushort)(r >> 16);
}
__device__ inline float bf2f(ushort u) {
  union { unsigned u; float f; } v{((unsigned)u) << 16};
  return v.f;
}
__device__ inline unsigned fbits(float f) {
  union { float f; unsigned u; } v{f};
  return v.u;
}

__device__ inline void gload16(const ushort* g, ushort* l) {
  __builtin_amdgcn_global_load_lds(
      (const __attribute__((address_space(1))) unsigned*)g,
      (__attribute__((address_space(3))) unsigned*)l, 16, 0, 0);
}

#define PHASE_BAR()                          \
  do {                                       \
    __builtin_amdgcn_sched_barrier(0);       \
    __builtin_amdgcn_s_barrier();            \
    __builtin_amdgcn_sched_barrier(0);       \
  } while (0)

// ---------------- fused fp32 -> bf16 convert (all 5 tensors, 1 launch) ----------------
__global__ __launch_bounds__(256) void cvt_all(const float* __restrict__ x,
                                               const float* __restrict__ wq,
                                               const float* __restrict__ wk,
                                               const float* __restrict__ wv,
                                               const float* __restrict__ wo,
                                               ushort* __restrict__ xb,
                                               ushort* __restrict__ wqkv,
                                               ushort* __restrict__ wob) {
  size_t e = (size_t)(blockIdx.x * blockDim.x + threadIdx.x) * 8;
  const float* src;
  ushort* dst;
  if (e < 8388608u) { src = x + e; dst = xb + e; }
  else if (e < 12582912u) { size_t o = e - 8388608u; src = wq + o; dst = wqkv + o; }
  else if (e < 13631488u) { size_t o = e - 12582912u; src = wk + o; dst = wqkv + 4194304u + o; }
  else if (e < 14680064u) { size_t o = e - 13631488u; src = wv + o; dst = wqkv + 5242880u + o; }
  else { size_t o = e - 14680064u; src = wo + o; dst = wob + o; }
  float4 v0 = ((const float4*)src)[0];
  float4 v1 = ((const float4*)src)[1];
  union { uint4 v; ushort u[8]; } pk;
  pk.u[0] = f2bf(v0.x); pk.u[1] = f2bf(v0.y); pk.u[2] = f2bf(v0.z); pk.u[3] = f2bf(v0.w);
  pk.u[4] = f2bf(v1.x); pk.u[5] = f2bf(v1.y); pk.u[6] = f2bf(v1.z); pk.u[7] = f2bf(v1.w);
  *(uint4*)dst = pk.v;
}

// ---------------- 8-phase bf16 GEMM template: C[M,N] = A * B^T -----------------------
// v15 = v13 schedule (per-phase staging, vmcnt(0) per K-tile, bank swizzle) +
// XCD-CHUNKED block swizzle (T1): 1-D grid, nb = (bid%8)*(nwg/8) + bid/8.
// Consecutive nb within one XCD share the same A-panel (x fastest) -> per-XCD
// L2 A-panel reuse ~6x better than round-robin. Pure index remap, no sync edit.
template <int BN, int MODE, typename OutT>
__global__ __launch_bounds__(512) void gemm8p(const ushort* __restrict__ Ag,
                                              const ushort* __restrict__ Bg,
                                              OutT* __restrict__ C,
                                              const float* __restrict__ fc,
                                              const float* __restrict__ fs,
                                              int M, int N, int K) {
  constexpr int NF = BN / 64;  // per-wave 16-col fragments
  __shared__ ushort As[2][2][256][32];
  __shared__ ushort Bs[2][2][BN][32];
  const int tid = threadIdx.x;
  const int lane = tid & 63, wave = tid >> 6;
  const int quad = lane >> 4, l16 = lane & 15;
  const int wm = wave >> 2, wn = wave & 3;  // 2M x 4N

  // XCD-chunked swizzle (grid is 1-D, nwg % 8 == 0)
  const int nwg = gridDim.x;
  const int nb = (blockIdx.x & 7) * (nwg >> 3) + (blockIdx.x >> 3);
  const int NX = N / BN;
  const int m0 = (nb / NX) * 256, n0 = (nb % NX) * BN;
  const int NT = K >> 6;

  // stage: lane's 16B lands at LDS row lrow = r0+(lane>>2), chunk lane&3.
  // That physical slot must hold logical chunk (lane&3)^((lrow>>1)&3).
  auto stA = [&](int Tn, int h) {
    const int r0 = h * 128 + wave * 16;
    const int lrow = r0 + (lane >> 2);
    const int sw = ((lane & 3) ^ ((lrow >> 1) & 3)) * 8;
    const ushort* g = Ag + (size_t)(m0 + lrow) * K + Tn * 64 + sw;
    gload16(g, &As[Tn & 1][0][r0][0]);
    gload16(g + 32, &As[Tn & 1][1][r0][0]);
  };
  auto stB = [&](int Tn, int h) {
    const int r0 = h * 128 + wave * 16;
    const int lrow = r0 + (lane >> 2);
    const int sw = ((lane & 3) ^ ((lrow >> 1) & 3)) * 8;
    const ushort* g = Bg + (size_t)(n0 + lrow) * K + Tn * 64 + sw;
    gload16(g, &Bs[Tn & 1][0][r0][0]);
    gload16(g + 32, &Bs[Tn & 1][1][r0][0]);
  };

  f32x4 acc[8][NF] = {};

  // prologue: stage K-tile 0 fully
  stA(0, 0); stA(0, 1);
  stB(0, 0);
  if constexpr (BN == 256) stB(0, 1);

  for (int T = 0; T < NT; ++T) {
    const int bf = T & 1;
    asm volatile("s_waitcnt vmcnt(0)" ::: "memory");
    PHASE_BAR();

    // B-frags for the whole K-tile (phase 0 reads, swizzled chunk)
    short8 bfr[NF][2];
#pragma unroll
    for (int nf = 0; nf < NF; nf++) {
      const int row = wn * (16 * NF) + nf * 16 + l16;
      const int ch = (quad ^ ((row >> 1) & 3)) * 8;
#pragma unroll
      for (int kk = 0; kk < 2; kk++)
        bfr[nf][kk] = *(short8*)&Bs[bf][kk][row][ch];
    }

#pragma unroll
    for (int q = 0; q < 4; q++) {
      short8 afr[2][2];
#pragma unroll
      for (int mq = 0; mq < 2; mq++) {
        const int row = wm * 128 + (2 * q + mq) * 16 + l16;
        const int ch = (quad ^ ((row >> 1) & 3)) * 8;
#pragma unroll
        for (int kk = 0; kk < 2; kk++)
          afr[mq][kk] = *(short8*)&As[bf][kk][row][ch];
      }

      // per-phase staging of tile T+1 into the other buffer (v8 schedule)
      if (T + 1 < NT) {
        if (q == 0) stA(T + 1, 0);
        else if (q == 1) stA(T + 1, 1);
        else if (q == 2) stB(T + 1, 0);
        else if constexpr (BN == 256) stB(T + 1, 1);
      }

      __builtin_amdgcn_s_setprio(1);
#pragma unroll
      for (int mq = 0; mq < 2; mq++)
#pragma unroll
        for (int nf = 0; nf < NF; nf++)
#pragma unroll
          for (int kk = 0; kk < 2; kk++)
            acc[2 * q + mq][nf] = __builtin_amdgcn_mfma_f32_16x16x32_bf16(
                afr[mq][kk], bfr[nf][kk], acc[2 * q + mq][nf], 0, 0, 0);
      __builtin_amdgcn_s_setprio(0);
      PHASE_BAR();
    }
  }

  // ---------------- epilogue ----------------
  if constexpr (MODE == 1) {
    // fused RoPE (Q/K regions) or passthrough (V region)
    if (n0 < 2560) {
      const float scale = (n0 < 2048) ? 0.125f * LOG2E : 1.0f;
      const int d0 = l16, d1 = l16 + 32;
      const int e0 = l16 + 16, e1 = l16 + 48;
#pragma unroll
      for (int mf = 0; mf < 8; mf++) {
#pragma unroll
        for (int r = 0; r < 4; r++) {
          size_t rg = (size_t)(m0 + wm * 128 + mf * 16 + quad * 4 + r);
          int s = (int)(rg & (SEQ - 1));
          const float* cb = fc + s * HDIM;
          const float* sb = fs + s * HDIM;
          float x0 = acc[mf][0][r], x2 = acc[mf][2][r];
          float y1 = acc[mf][1][r], y3 = acc[mf][3][r];
          float o0 = (x0 * cb[d0] - x2 * sb[d0]) * scale;
          float o2 = (x2 * cb[d1] + x0 * sb[d1]) * scale;
          float o1 = (y1 * cb[e0] - y3 * sb[e0]) * scale;
          float o3 = (y3 * cb[e1] + y1 * sb[e1]) * scale;
          ushort* Cr = (ushort*)C + rg * N + n0 + wn * 64 + l16;
          Cr[0]  = f2bf(o0);
          Cr[16] = f2bf(o1);
          Cr[32] = f2bf(o2);
          Cr[48] = f2bf(o3);
        }
      }
      return;
    }
  }
#pragma unroll
  for (int mf = 0; mf < 8; mf++) {
#pragma unroll
    for (int r = 0; r < 4; r++) {
      size_t rg = (size_t)(m0 + wm * 128 + mf * 16 + quad * 4 + r);
#pragma unroll
      for (int nf = 0; nf < NF; nf++) {
        int cg = n0 + wn * (16 * NF) + nf * 16 + l16;
        if constexpr (sizeof(OutT) == 2)
          C[rg * N + cg] = f2bf(acc[mf][nf][r]);
        else
          C[rg * N + cg] = acc[mf][nf][r];
      }
    }
  }
}

// ---------------- MFMA flash attention v9 ----------------
// v12 body + KV-panel->XCD colocation: decode bh so XCD (=bid%8) equals kh.
// Old decode spread each (b,kh) KV panel (512KB) over 4 XCDs and packed 8
// panels (4MB) per XCD L2; new decode gives each XCD 2 panels (1MB) -> K/V
// staging loads become near-pure L2 hits. CU-balance (qblk from bid>>6) kept.
__global__ __launch_bounds__(256, 4) void attn_mfma(const ushort* __restrict__ QKV,
                                                    ushort* __restrict__ O) {
  __shared__ ushort Ks[64][72];     // [key][d]
  __shared__ ushort Vt[64][72];     // [d][key]
  __shared__ ushort Pw[4][16][72];  // per-wave P[q][key], reused per frag
  const int tid = threadIdx.x;
  const int lane = tid & 63, wave = tid >> 6;
  const int quad = lane >> 4, l16 = lane & 15;

  // CU-balanced qblk + XCD-colocated (b,h) derivation
  const int bid = blockIdx.x;
  const int qq = bid >> 8;         // quarter 0..3
  const int j4 = (bid >> 6) & 3;   // 0..3
  const int qblk = (qq >> 1) * 8 + ((qq & 1) ? 7 - j4 : j4);

  const int c6 = bid & 63;
  const int kh = c6 & 7;           // XCD = bid%8 = kh
  const int b = (c6 >> 3) & 1;
  const int h = kh * 4 + (c6 >> 4);

  const int ntiles = 2 * qblk + 2;          // causal K-range of this 128-row block
  const int wrow = qblk * 128 + wave * 32;  // this wave's first q row (global)

  // Q fragments: f=0 rows [wrow, wrow+16), f=1 rows [wrow+16, wrow+32)
  short8 qf[2][2];
#pragma unroll
  for (int f = 0; f < 2; f++)
#pragma unroll
    for (int c = 0; c < 2; c++)
      qf[f][c] = *(const short8*)(QKV +
          (size_t)(b * SEQ + wrow + f * 16 + l16) * QKV_LD +
          h * HDIM + c * 32 + quad * 8);

  f32x4 o[2][4] = {};
  float m[2] = {-INFINITY, -INFINITY}, l[2] = {0.f, 0.f};  // l is per-LANE partial

  const ushort* Kbase = QKV + (size_t)b * SEQ * QKV_LD + 2048 + kh * HDIM;
  const ushort* Vbase = Kbase + 512;
  const int kp = tid & 31, dg = tid >> 5;

  for (int t = 0; t < ntiles; t++) {
    const int k0 = t * 64;
    __syncthreads();
    {
      const float4* kpp = (const float4*)(Kbase + (size_t)(k0 + lane) * QKV_LD + wave * 16);
      float4 kv0 = kpp[0], kv1 = kpp[1];
      const uint4* va4 = (const uint4*)(Vbase + (size_t)(k0 + 2 * kp) * QKV_LD + dg * 8);
      const uint4* vb4 = (const uint4*)(Vbase + (size_t)(k0 + 2 * kp + 1) * QKV_LD + dg * 8);
      uint4 va = va4[0], vb = vb4[0];
      *(float4*)&Ks[lane][wave * 16] = kv0;
      *(float4*)&Ks[lane][wave * 16 + 8] = kv1;
      const unsigned* vaw = (const unsigned*)&va;
      const unsigned* vbw = (const unsigned*)&vb;
#pragma unroll
      for (int j = 0; j < 8; j++) {
        unsigned pk = (j & 1)
            ? __builtin_amdgcn_perm(vbw[j >> 1], vaw[j >> 1], 0x07060302)
            : __builtin_amdgcn_perm(vbw[j >> 1], vaw[j >> 1], 0x05040100);
        *(unsigned*)&Vt[dg * 8 + j][2 * kp] = pk;
      }
    }
    __syncthreads();

    // wave fully below diagonal? (both frags fully masked -> only staging needed)
    if (k0 > wrow + 31) continue;
    const bool a0 = (k0 <= wrow + 15);  // frag 0 has any active keys

    // QK^T for both frags, kf shared
    f32x4 s0[4], s1[4];
    __builtin_amdgcn_s_setprio(1);
#pragma unroll
    for (int nt = 0; nt < 4; nt++) {
      short8 kf0 = *(short8*)&Ks[nt * 16 + l16][quad * 8];
      short8 kf1 = *(short8*)&Ks[nt * 16 + l16][32 + quad * 8];
      f32x4 z1 = {};
      z1 = __builtin_amdgcn_mfma_f32_16x16x32_bf16(kf0, qf[1][0], z1, 0, 0, 0);
      s1[nt] = __builtin_amdgcn_mfma_f32_16x16x32_bf16(kf1, qf[1][1], z1, 0, 0, 0);
      if (a0) {
        f32x4 z0 = {};
        z0 = __builtin_amdgcn_mfma_f32_16x16x32_bf16(kf0, qf[0][0], z0, 0, 0, 0);
        s0[nt] = __builtin_amdgcn_mfma_f32_16x16x32_bf16(kf1, qf[0][1], z0, 0, 0, 0);
      }
    }
    __builtin_amdgcn_s_setprio(0);

    // causal masking (diagonal region only)
    if (k0 + 63 > wrow + 16) {  // frag 1 diagonal
      const int lim1 = wrow + 16 + l16 - k0;
#pragma unroll
      for (int nt = 0; nt < 4; nt++)
#pragma unroll
        for (int r = 0; r < 4; r++)
          if (nt * 16 + quad * 4 + r > lim1) s1[nt][r] = -INFINITY;
    }
    if (a0 && k0 + 63 > wrow) {  // frag 0 diagonal
      const int lim0 = wrow + l16 - k0;
#pragma unroll
      for (int nt = 0; nt < 4; nt++)
#pragma unroll
        for (int r = 0; r < 4; r++)
          if (nt * 16 + quad * 4 + r > lim0) s0[nt][r] = -INFINITY;
    }

    // online softmax: T13 defer-max + ballot-gated shuffles + per-lane partial l
    auto smx = [&](f32x4 (&s)[4], float& mm, float& ll, f32x4 (&oo)[4]) {
      float mx = s[0][0];
#pragma unroll
      for (int nt = 0; nt < 4; nt++)
#pragma unroll
        for (int r = 0; r < 4; r++) mx = fmaxf(mx, s[nt][r]);
      // __all over lane-partials == __all over row-maxima: shuffle-free gate
      if (!__all(mx <= mm + 8.f)) {
        mx = fmaxf(mx, __shfl_xor(mx, 16));
        mx = fmaxf(mx, __shfl_xor(mx, 32));
        float mnew = fmaxf(mm, mx);
        float al = hw_exp2(mm - mnew);  // row-uniform -> valid for per-lane ll
        mm = mnew;
        ll *= al;
#pragma unroll
        for (int dt = 0; dt < 4; dt++)
#pragma unroll
          for (int r = 0; r < 4; r++) oo[dt][r] *= al;
      }
      float psum = 0.f;
#pragma unroll
      for (int nt = 0; nt < 4; nt++) {
        float p0 = hw_exp2(s[nt][0] - mm), p1 = hw_exp2(s[nt][1] - mm);
        float p2 = hw_exp2(s[nt][2] - mm), p3 = hw_exp2(s[nt][3] - mm);
        psum += (p0 + p1) + (p2 + p3);
        unsigned lo = __builtin_amdgcn_perm(fbits(p1), fbits(p0), 0x07060302);
        unsigned hi = __builtin_amdgcn_perm(fbits(p3), fbits(p2), 0x07060302);
        uint2 pk; pk.x = lo; pk.y = hi;
        *(uint2*)&Pw[wave][l16][nt * 16 + quad * 4] = pk;
      }
      ll += psum;  // per-lane partial; quad-reduced in epilogue
    };

    short8 pf00, pf01, pf10, pf11;
    if (a0) {
      smx(s0, m[0], l[0], o[0]);
      pf00 = *(short8*)&Pw[wave][l16][quad * 8];
      pf01 = *(short8*)&Pw[wave][l16][32 + quad * 8];
    }
    smx(s1, m[1], l[1], o[1]);
    pf10 = *(short8*)&Pw[wave][l16][quad * 8];
    pf11 = *(short8*)&Pw[wave][l16][32 + quad * 8];

    // PV for both frags, vf shared
    __builtin_amdgcn_s_setprio(1);
#pragma unroll
    for (int dt = 0; dt < 4; dt++) {
      short8 vf0 = *(short8*)&Vt[dt * 16 + l16][quad * 8];
      short8 vf1 = *(short8*)&Vt[dt * 16 + l16][32 + quad * 8];
      o[1][dt] = __builtin_amdgcn_mfma_f32_16x16x32_bf16(vf0, pf10, o[1][dt], 0, 0, 0);
      o[1][dt] = __builtin_amdgcn_mfma_f32_16x16x32_bf16(vf1, pf11, o[1][dt], 0, 0, 0);
      if (a0) {
        o[0][dt] = __builtin_amdgcn_mfma_f32_16x16x32_bf16(vf0, pf00, o[0][dt], 0, 0, 0);
        o[0][dt] = __builtin_amdgcn_mfma_f32_16x16x32_bf16(vf1, pf01, o[0][dt], 0, 0, 0);
      }
    }
    __builtin_amdgcn_s_setprio(0);
  }

#pragma unroll
  for (int f = 0; f < 2; f++) {
    // quad-reduce the per-lane partial l (once per frag)
    float lr = l[f];
    lr += __shfl_xor(lr, 16);
    lr += __shfl_xor(lr, 32);
    float inv = 1.0f / lr;
    size_t rowg = (size_t)(b * SEQ + wrow + f * 16 + l16) * EMBED + h * HDIM;
#pragma unroll
    for (int dt = 0; dt < 4; dt++) {
      ushort q0 = f2bf(o[f][dt][0] * inv), q1 = f2bf(o[f][dt][1] * inv);
      ushort q2 = f2bf(o[f][dt][2] * inv), q3 = f2bf(o[f][dt][3] * inv);
      uint2 pk;
      pk.x = (unsigned)q0 | ((unsigned)q1 << 16);
      pk.y = (unsigned)q2 | ((unsigned)q3 << 16);
      *(uint2*)&O[rowg + dt * 16 + quad * 4] = pk;
    }
  }
}

// ---------------- launch ----------------
extern "C" void kernel_launch(void* const* d_in, const int* in_sizes, int n_in,
                              void* d_out, int out_size, void* d_ws, size_t ws_size,
                              hipStream_t stream) {
  const float* x = (const float*)d_in[0];
  const float* fcos = (const float*)d_in[1];
  const float* fsin = (const float*)d_in[2];
  const float* wq = (const float*)d_in[3];
  const float* wk = (const float*)d_in[4];
  const float* wv = (const float*)d_in[5];
  const float* wo = (const float*)d_in[6];
  float* out = (float*)d_out;

  const int M = BATCH * SEQ;  // 4096
  ushort* ws = (ushort*)d_ws;
  ushort* xb = ws;
  ushort* wqkv = xb + (size_t)M * EMBED;
  ushort* wob = wqkv + (size_t)QKV_LD * EMBED;
  ushort* QKVb = wob + (size_t)EMBED * EMBED;
  ushort* Ab = QKVb + (size_t)M * QKV_LD;

  dim3 blk(256);
  cvt_all<<<9216, blk, 0, stream>>>(x, wq, wk, wv, wo, xb, wqkv, wob);

  // QKV projection + fused RoPE: 8-phase GEMM, XCD-chunked 1-D grid (192 blocks)
  gemm8p<256, 1, ushort><<<dim3(192), dim3(512), 0, stream>>>(
      xb, wqkv, QKVb, fcos, fsin, M, QKV_LD, EMBED);

  attn_mfma<<<dim3(1024), blk, 0, stream>>>(QKVb, Ab);

  // output projection: 8-phase GEMM, XCD-chunked 1-D grid (256 blocks)
  gemm8p<128, 0, float><<<dim3(256), dim3(512), 0, stream>>>(
      Ab, wob, out, nullptr, nullptr, M, EMBED, EMBED);
}